// Round 11
// baseline (5031.066 us; speedup 1.0000x reference)
//
#include <hip/hip_runtime.h>
#include <hip/hip_bf16.h>
#include <math.h>

#define BATCH 128
#define LEN   64000
#define FS    256
#define STEPS 200
#define NFILT 64
#define HID   512
#define HID2  512
#define NOUT  10
#define NF    320
#define G4    2048
#define KTOT  1024
#define NBLK  256
#define HSLOT (BATCH * HID2)

typedef __bf16  bf16x8 __attribute__((ext_vector_type(8)));
typedef float   f32x4  __attribute__((ext_vector_type(4)));
typedef __hip_bfloat16 hbf;

// gbar region word layout (stride-16 lines)
#define ARV(b)  (128 + (b) * 16)
#define REL_(i) (128 + 4096 + (i) * 16)
#define BAR_WORDS (128 + 4096 + 128)

// ---------------------------------------------------------------------------
__device__ __forceinline__ float fsig(float x) { return 1.f / (1.f + __expf(-x)); }
__device__ __forceinline__ float ftanh(float x) { return 1.f - 2.f / (__expf(2.f * x) + 1.f); }
__device__ __forceinline__ void imulf_(float al, float au, float bl, float bu,
                                       float& lo, float& hi) {
    const float p1 = al * bl, p2 = al * bu, p3 = au * bl, p4 = au * bu;
    lo = fminf(fminf(p1, p2), fminf(p3, p4));
    hi = fmaxf(fmaxf(p1, p2), fmaxf(p3, p4));
}

// ---- flags: relaxed agent atomics (R9-proven); ordering via fences -------
__device__ __forceinline__ unsigned ld_flag(const unsigned* p) {
    return __hip_atomic_load(p, __ATOMIC_RELAXED, __HIP_MEMORY_SCOPE_AGENT);
}
__device__ __forceinline__ void st_flag(unsigned* p, unsigned v) {
    __hip_atomic_store(p, v, __ATOMIC_RELAXED, __HIP_MEMORY_SCOPE_AGENT);
}

// ---------------------------------------------------------------------------
// Frontend (unchanged, verified)
// ---------------------------------------------------------------------------
__global__ __launch_bounds__(512) void frontend_kernel(
    const float* __restrict__ lb, const float* __restrict__ ub,
    const float* __restrict__ mtx1, const float* __restrict__ mtx2,
    const float* __restrict__ lin1_w, const float* __restrict__ lin1_b,
    hbf* __restrict__ Xc, hbf* __restrict__ Xr)
{
    const int tid  = threadIdx.x;
    const int r    = tid >> 6;
    const int lane = tid & 63;
    const int rowid = blockIdx.x * 8 + r;
    const int f = rowid % NF;
    const int b = rowid / NF;

    __shared__ float sc[8][FS], sr[8][FS];
    __shared__ float s2c[8][FS + 2], s2r[8][FS + 2];
    __shared__ float s3c[8][NFILT], s3r[8][NFILT];

    for (int i = lane; i < FS; i += 64) {
        const int pos = f * STEPS + i;
        float l = 0.f, u = 0.f;
        if (pos < LEN) {
            l = lb[(size_t)b * LEN + pos];
            u = ub[(size_t)b * LEN + pos];
        }
        sc[r][i] = 0.5f * (l + u);
        sr[r][i] = 0.5f * (u - l);
    }
    __syncthreads();

    for (int j = lane; j < FS + 2; j += 64) {
        float oc = 0.f, orr = 0.f;
#pragma unroll 4
        for (int i = 0; i < FS; ++i) {
            const float w = mtx1[i * (FS + 2) + j];
            oc  = fmaf(sc[r][i], w, oc);
            orr = fmaf(sr[r][i], fabsf(w), orr);
        }
        const float l1l = oc - orr, l1u = oc + orr;
        const float a = l1l * l1l, bb = l1u * l1u;
        const float squ = fmaxf(a, bb);
        const float sql = (l1l <= 0.f && l1u >= 0.f) ? 0.f : fminf(a, bb);
        s2c[r][j] = 0.5f * (sql + squ);
        s2r[r][j] = 0.5f * (squ - sql);
    }
    __syncthreads();

    {
        const int j = lane;
        float oc = 1e-10f, orr = 0.f;
#pragma unroll 4
        for (int i = 0; i < FS + 2; ++i) {
            const float w = mtx2[i * NFILT + j];
            oc  = fmaf(s2c[r][i], w, oc);
            orr = fmaf(s2r[r][i], fabsf(w), orr);
        }
        const float lgl = logf(oc - orr);
        const float lgu = logf(oc + orr);
        s3c[r][j] = 0.5f * (lgl + lgu);
        s3r[r][j] = 0.5f * (lgu - lgl);
    }
    __syncthreads();

    for (int j = lane; j < HID; j += 64) {
        float oc = lin1_b[j], orr = 0.f;
#pragma unroll 4
        for (int i = 0; i < NFILT; ++i) {
            const float w = lin1_w[i * HID + j];
            oc  = fmaf(s3c[r][i], w, oc);
            orr = fmaf(s3r[r][i], fabsf(w), orr);
        }
        const float n1l = oc - orr, n1u = oc + orr;
        const float rl = fmaxf(n1l, 0.f), ru = fmaxf(n1u, 0.f);
        const size_t o = ((size_t)f * BATCH + b) * HID + j;
        Xc[o] = __float2bfloat16(0.5f * (rl + ru));
        Xr[o] = __float2bfloat16(0.5f * (ru - rl));
    }
}

// ---------------------------------------------------------------------------
__global__ __launch_bounds__(256) void prep_weights_kernel(
    const float* __restrict__ wih, const float* __restrict__ whh,
    hbf* __restrict__ Wt)
{
    __shared__ float tile[32][33];
    const int n0 = blockIdx.x * 32;
    const int k0 = blockIdx.y * 32;
    const int tx = threadIdx.x & 31;
    const int ty = threadIdx.x >> 5;

    for (int r = ty; r < 32; r += 8) {
        const int k = k0 + r;
        const float* src = (k < HID) ? (wih + (size_t)k * G4)
                                     : (whh + (size_t)(k - HID) * G4);
        tile[r][tx] = src[n0 + tx];
    }
    __syncthreads();
    for (int r = ty; r < 32; r += 8) {
        const int n = n0 + r;
        Wt[(size_t)n * KTOT + k0 + tx] = __float2bfloat16(tile[tx][r]);
    }
}

// ---------------------------------------------------------------------------
// One-time global barrier for registration (R7-proven).
// ---------------------------------------------------------------------------
__device__ __forceinline__ void gbar(unsigned* bar, unsigned gen,
                                     int bid, int tid) {
    __builtin_amdgcn_s_waitcnt(0);
    __syncthreads();
    if (bid == 0) {
        if (tid != 0) {
            while (ld_flag(&bar[ARV(tid)]) < gen)
                __builtin_amdgcn_s_sleep(1);
        }
        __syncthreads();
        if (tid < 8) st_flag(&bar[REL_(tid)], gen);
    } else {
        if (tid == 0) {
            st_flag(&bar[ARV(bid)], gen);
            while (ld_flag(&bar[REL_(bid & 7)]) < gen)
                __builtin_amdgcn_s_sleep(4);
        }
        asm volatile("" ::: "memory");
    }
    __syncthreads();
}

// ---------------------------------------------------------------------------
__device__ __forceinline__ void cell_elem(
    const float C[4], const float R[4], const float bs[4],
    float& cl_r, float& cu_r, float& nhl, float& nhu)
{
    float gl[4], gu[4];
#pragma unroll
    for (int g = 0; g < 4; ++g) {
        gl[g] = C[g] - R[g] + bs[g];
        gu[g] = C[g] + R[g] + bs[g];
    }
    const float il = fsig(gl[0]), iu = fsig(gu[0]);
    const float fl = fsig(gl[1]), fu = fsig(gu[1]);
    const float ggl = ftanh(gl[2]), ggu = ftanh(gu[2]);
    const float ol = fsig(gl[3]), ou = fsig(gu[3]);

    float fcl, fcu, igl, igu;
    imulf_(fl, fu, cl_r, cu_r, fcl, fcu);
    imulf_(il, iu, ggl, ggu, igl, igu);
    const float ncl = fcl + igl, ncu = fcu + igu;
    cl_r = ncl; cu_r = ncu;
    imulf_(ol, ou, ftanh(ncl), ftanh(ncu), nhl, nhu);
}

// GEMM over one K-half from LDS weights; MASKED is a literal 0/1.
#define GEMM_HALF(KBASE, MASKED)                                               \
    _Pragma("unroll")                                                          \
    for (int kk = 0; kk < 16; ++kk) {                                          \
        const int KK = (KBASE) + kk;                                           \
        _Pragma("unroll")                                                      \
        for (int g = 0; g < 4; ++g) {                                          \
            union { bf16x8 v; unsigned u[4]; } t2;                             \
            t2.v = *(const bf16x8*)&Wlds[(size_t)(((g << 5) | KK) * 64 + lane) * 8]; \
            if (MASKED) {                                                      \
                t2.u[0] &= 0x7FFF7FFFu; t2.u[1] &= 0x7FFF7FFFu;                \
                t2.u[2] &= 0x7FFF7FFFu; t2.u[3] &= 0x7FFF7FFFu;                \
            }                                                                  \
            acc[g] = __builtin_amdgcn_mfma_f32_16x16x32_bf16(af[kk], t2.v, acc[g], 0, 0, 0); \
        }                                                                      \
    }

#define LOADA16(PTR)                                                           \
    _Pragma("unroll")                                                          \
    for (int i = 0; i < 16; ++i) af[i] = *(const bf16x8*)((PTR) + 32 * i);

// ---------------------------------------------------------------------------
// Persistent LSTM. Group = physical XCD when dispatch is balanced (XCC_ID
// registration, R6-proven), else static mapping — both correct: all H
// exchange uses PLAIN cached loads/stores ordered by official agent-scope
// acquire/release fences (weights live in LDS, so L2 invalidation is cheap
// now). Flags are relaxed agent atomics. No hand-rolled cache-scope asm.
// ---------------------------------------------------------------------------
__global__ __launch_bounds__(256, 1) void lstm_persistent(
    const hbf* __restrict__ Xc, const hbf* __restrict__ Xr,
    const hbf* __restrict__ Wt0, const hbf* __restrict__ Wt1,
    const float* __restrict__ b0, const float* __restrict__ b1,
    hbf* __restrict__ RingC, hbf* __restrict__ RingR,          // NF slots
    hbf* __restrict__ L0c0, hbf* __restrict__ L0r0,
    hbf* __restrict__ L0c1, hbf* __restrict__ L0r1,
    hbf* __restrict__ L1c0, hbf* __restrict__ L1r0,
    hbf* __restrict__ L1c1, hbf* __restrict__ L1r1,
    float* __restrict__ h1l, float* __restrict__ h1u,
    unsigned* __restrict__ bar, unsigned* __restrict__ tkt,
    unsigned* __restrict__ lflags, unsigned* __restrict__ cflags)
{
    const int tid = threadIdx.x;
    const int bid = blockIdx.x;

    __shared__ unsigned s_info, s_map;
    __shared__ int s_fast;
    __shared__ hbf   Wlds[4 * 32 * 64 * 8];      // 128 KB [g][KK][lane][8]
    __shared__ float red[2][2][4][64][4];        // 16 KB [op][mh][g][lane][reg]

    // ---- registration: physical XCD + ticket ----
    if (tid == 0) {
        unsigned xcc;
        asm volatile("s_getreg_b32 %0, hwreg(HW_REG_XCC_ID)" : "=s"(xcc));
        xcc &= 7u;
        const unsigned slot = __hip_atomic_fetch_add(
            &tkt[xcc * 16], 1u, __ATOMIC_RELAXED, __HIP_MEMORY_SCOPE_AGENT);
        s_info = (xcc << 16) | slot;
    }
    gbar(bar, 1, bid, tid);
    if (tid == 0) {
        unsigned cnt[8]; bool ok = true;
        for (int y = 0; y < 8; ++y) {
            cnt[y] = ld_flag(&tkt[y * 16]);
            ok = ok && (cnt[y] == 32u);
        }
        const unsigned xcc = s_info >> 16, slot = s_info & 0xffffu;
        unsigned rank;
        if (ok) rank = xcc * 32u + slot;
        else { rank = slot; for (unsigned y = 0; y < xcc; ++y) rank += cnt[y]; }
        s_map = rank; s_fast = ok ? 1 : 0;
    }
    __syncthreads();

    const unsigned rank = s_map;
    int layer, mgrp, jslot;
    if (s_fast) { layer = (rank >> 5) & 1; mgrp = rank >> 6; jslot = rank & 31; }
    else        { layer = rank >> 7; mgrp = (rank >> 5) & 3; jslot = rank & 31; }
    const int m0 = mgrp * 32;
    const int j0 = jslot * 16;
    const int lfbase = layer * 128 + mgrp * 32;
    const int cfbase = mgrp * 32;
    const int myLf = lfbase + jslot;
    const int myCf = cfbase + jslot;

    // ---- stage weight slice into LDS ----
    {
        const hbf* Wt = layer ? Wt1 : Wt0;
        for (int c = tid; c < 8192; c += 256) {
            const int g  = c >> 11;
            const int kk = (c >> 6) & 31;
            const int l6 = c & 63;
            const int n  = g * HID2 + j0 + (l6 & 15);
            const int k  = kk * 32 + (l6 >> 4) * 8;
            *(ulonglong2*)&Wlds[(size_t)c * 8] =
                *(const ulonglong2*)(Wt + (size_t)n * KTOT + k);
        }
    }

    const int w    = tid >> 6;
    const int lane = tid & 63;
    const int op   = w & 1;                  // 0 center, 1 radius
    const int mh   = w >> 1;                 // m-half
    const int rc   = lane & 15;
    const int gk   = lane >> 4;
    const int aoff = (m0 + mh * 16 + rc) * 512 + 8 * gk;

    hbf* Lc[2] = { layer ? L1c0 : L0c0, layer ? L1c1 : L0c1 };
    hbf* Lr[2] = { layer ? L1r0 : L0r0, layer ? L1r1 : L0r1 };

    // cell-phase constants
    const int mm  = tid >> 4;
    const int cj  = tid & 15;
    const int ll  = ((mm >> 2) << 4) | cj;
    const int rr  = mm & 3;
    const int idx0 = (m0 + mm) * HID2 + j0 + cj;
    const int idx1 = idx0 + 16 * HID2;
    const float* bias = layer ? b1 : b0;
    float bs[4];
#pragma unroll
    for (int g = 0; g < 4; ++g) bs[g] = bias[g * HID2 + j0 + cj];

    float cAl = 0.f, cAu = 0.f, cBl = 0.f, cBu = 0.f;
    float svAc = 0.f, svAr = 0.f, svBc = 0.f, svBr = 0.f;   // L0 ring carry

    __syncthreads();                         // Wlds ready

    for (int t = 0; t < NF; ++t) {
        const int wslot = t & 1, rslot = wslot ^ 1;
        f32x4 acc[4] = {f32x4{0,0,0,0}, f32x4{0,0,0,0},
                        f32x4{0,0,0,0}, f32x4{0,0,0,0}};
        bf16x8 af[16];

        if (layer == 0) {
            // x-half on X[t]: no sync needed, runs before the poll
            {
                const hbf* p = (op ? Xr : Xc) + (size_t)t * HSLOT + aoff;
                LOADA16(p)
                if (op) { GEMM_HALF(0, 1) } else { GEMM_HALF(0, 0) }
            }
            // poll own group >= t, then acquire
            if (tid < 64) {
                const unsigned* p = &lflags[(lfbase + (tid & 31)) * 16];
                for (;;) {
                    const unsigned v = ld_flag(p);
                    if (__all((int)v >= t)) break;
                    __builtin_amdgcn_s_sleep(2);
                }
                __builtin_amdgcn_fence(__ATOMIC_ACQUIRE, "agent");
            }
            __syncthreads();
            // h-half on H0loc[rslot] (plain cached loads)
            {
                const hbf* p = (op ? Lr[rslot] : Lc[rslot]) + aoff;
                LOADA16(p)
            }
            // ring stores of step t-1 (plain; flushed by this step's release)
            if (t > 0) {
                const size_t rb = (size_t)(t - 1) * HSLOT;
                RingC[rb + idx0] = __float2bfloat16(svAc);
                RingR[rb + idx0] = __float2bfloat16(svAr);
                RingC[rb + idx1] = __float2bfloat16(svBc);
                RingR[rb + idx1] = __float2bfloat16(svBr);
            }
            if (op) { GEMM_HALF(16, 1) } else { GEMM_HALF(16, 0) }
        } else {
            // poll own group >= t, then acquire
            if (tid < 64) {
                const unsigned* p = &lflags[(lfbase + (tid & 31)) * 16];
                for (;;) {
                    const unsigned v = ld_flag(p);
                    if (__all((int)v >= t)) break;
                    __builtin_amdgcn_s_sleep(2);
                }
                __builtin_amdgcn_fence(__ATOMIC_ACQUIRE, "agent");
            }
            __syncthreads();
            // h-half on H1loc[rslot]
            {
                const hbf* p = (op ? Lr[rslot] : Lc[rslot]) + aoff;
                LOADA16(p)
                if (op) { GEMM_HALF(16, 1) } else { GEMM_HALF(16, 0) }
            }
            // poll cross: ring slot t published (cflag >= t+1), then acquire
            if (tid < 64) {
                const unsigned* p = &cflags[(cfbase + (tid & 31)) * 16];
                for (;;) {
                    const unsigned v = ld_flag(p);
                    if (__all((int)v >= t + 1)) break;
                    __builtin_amdgcn_s_sleep(2);
                }
                __builtin_amdgcn_fence(__ATOMIC_ACQUIRE, "agent");
            }
            __syncthreads();
            // x-half on Ring[t] (plain cached loads)
            {
                const hbf* p = (op ? RingR : RingC) + (size_t)t * HSLOT + aoff;
                LOADA16(p)
                if (op) { GEMM_HALF(0, 1) } else { GEMM_HALF(0, 0) }
            }
        }

        // ---- reduce C/R across waves via LDS ----
#pragma unroll
        for (int g = 0; g < 4; ++g)
            *((f32x4*)&red[op][mh][g][lane][0]) = acc[g];
        __syncthreads();

        // ---- cell: 2 elements per thread (plain stores) ----
        {
            float C0[4], R0[4], C1[4], R1[4];
#pragma unroll
            for (int g = 0; g < 4; ++g) {
                C0[g] = red[0][0][g][ll][rr];
                R0[g] = red[1][0][g][ll][rr];
                C1[g] = red[0][1][g][ll][rr];
                R1[g] = red[1][1][g][ll][rr];
            }
            hbf* oc   = Lc[wslot];
            hbf* orr_ = Lr[wslot];
            const bool writeF = (layer == 1) && (t == NF - 1);

            float nhl, nhu;
            cell_elem(C0, R0, bs, cAl, cAu, nhl, nhu);
            float hc = 0.5f * (nhl + nhu), hr = 0.5f * (nhu - nhl);
            oc[idx0] = __float2bfloat16(hc);
            orr_[idx0] = __float2bfloat16(hr);
            if (layer == 0) { svAc = hc; svAr = hr; }
            if (writeF) { h1l[idx0] = nhl; h1u[idx0] = nhu; }

            cell_elem(C1, R1, bs, cBl, cBu, nhl, nhu);
            hc = 0.5f * (nhl + nhu); hr = 0.5f * (nhu - nhl);
            oc[idx1] = __float2bfloat16(hc);
            orr_[idx1] = __float2bfloat16(hr);
            if (layer == 0) { svBc = hc; svBr = hr; }
            if (writeF) { h1l[idx1] = nhl; h1u[idx1] = nhu; }
        }

        // ---- arrive: drain all waves' stores, release, then flags ----
        __builtin_amdgcn_s_waitcnt(0);
        __syncthreads();
        if (tid < 64) __builtin_amdgcn_fence(__ATOMIC_RELEASE, "agent");
        if (tid == 0) {
            st_flag(&lflags[myLf * 16], (unsigned)(t + 1));
            if (layer == 0 && t > 0)
                st_flag(&cflags[myCf * 16], (unsigned)t);
        }
    }

    // ---- L0 epilogue: publish ring slot NF-1, final cross flag ----
    if (layer == 0) {
        const size_t rb = (size_t)(NF - 1) * HSLOT;
        RingC[rb + idx0] = __float2bfloat16(svAc);
        RingR[rb + idx0] = __float2bfloat16(svAr);
        RingC[rb + idx1] = __float2bfloat16(svBc);
        RingR[rb + idx1] = __float2bfloat16(svBr);
        __builtin_amdgcn_s_waitcnt(0);
        __syncthreads();
        if (tid < 64) __builtin_amdgcn_fence(__ATOMIC_RELEASE, "agent");
        if (tid == 0) st_flag(&cflags[myCf * 16], (unsigned)NF);
    }
}

// ---------------------------------------------------------------------------
__global__ __launch_bounds__(64) void final_kernel(
    const float* __restrict__ h1l, const float* __restrict__ h1u,
    const float* __restrict__ w, const float* __restrict__ bias,
    float* __restrict__ out)
{
    const int b = blockIdx.x;
    const int j = threadIdx.x;
    if (j < NOUT) {
        float oc = bias[j], orr = 0.f;
        for (int i = 0; i < HID2; ++i) {
            const float lo = h1l[(size_t)b * HID2 + i];
            const float hi = h1u[(size_t)b * HID2 + i];
            const float wv = w[i * NOUT + j];
            oc  = fmaf(0.5f * (lo + hi), wv, oc);
            orr = fmaf(0.5f * (hi - lo), fabsf(wv), orr);
        }
        out[b * NOUT + j] = oc - orr;
        out[BATCH * NOUT + b * NOUT + j] = oc + orr;
    }
}

// ---------------------------------------------------------------------------
extern "C" void kernel_launch(void* const* d_in, const int* in_sizes, int n_in,
                              void* d_out, int out_size, void* d_ws, size_t ws_size,
                              hipStream_t stream)
{
    const float* input_lb = (const float*)d_in[0];
    const float* input_ub = (const float*)d_in[1];
    const float* mtx1     = (const float*)d_in[2];
    const float* mtx2     = (const float*)d_in[3];
    const float* lin1_w   = (const float*)d_in[4];
    const float* lin1_b   = (const float*)d_in[5];
    const float* w_ih0    = (const float*)d_in[6];
    const float* w_hh0    = (const float*)d_in[7];
    const float* b0       = (const float*)d_in[8];
    const float* w_ih1    = (const float*)d_in[9];
    const float* w_hh1    = (const float*)d_in[10];
    const float* b1       = (const float*)d_in[11];
    const float* lin2_w   = (const float*)d_in[12];
    const float* lin2_b   = (const float*)d_in[13];
    float* out = (float*)d_out;

    char* ws = (char*)d_ws;
    size_t off = 0;
    hbf* Xc = (hbf*)(ws + off); off += (size_t)NF * HSLOT * 2;
    hbf* Xr = (hbf*)(ws + off); off += (size_t)NF * HSLOT * 2;
    hbf* Wt0 = (hbf*)(ws + off); off += (size_t)G4 * KTOT * 2;
    hbf* Wt1 = (hbf*)(ws + off); off += (size_t)G4 * KTOT * 2;
    hbf* RingC = (hbf*)(ws + off); off += (size_t)NF * HSLOT * 2;
    hbf* RingR = (hbf*)(ws + off); off += (size_t)NF * HSLOT * 2;

    // zeroed-every-launch region
    char* zbase = ws + off;
    hbf* L0c0 = (hbf*)(ws + off); off += (size_t)HSLOT * 2;
    hbf* L0r0 = (hbf*)(ws + off); off += (size_t)HSLOT * 2;
    hbf* L0c1 = (hbf*)(ws + off); off += (size_t)HSLOT * 2;
    hbf* L0r1 = (hbf*)(ws + off); off += (size_t)HSLOT * 2;
    hbf* L1c0 = (hbf*)(ws + off); off += (size_t)HSLOT * 2;
    hbf* L1r0 = (hbf*)(ws + off); off += (size_t)HSLOT * 2;
    hbf* L1c1 = (hbf*)(ws + off); off += (size_t)HSLOT * 2;
    hbf* L1r1 = (hbf*)(ws + off); off += (size_t)HSLOT * 2;
    unsigned* lflags = (unsigned*)(ws + off); off += (size_t)256 * 16 * 4;
    unsigned* cflags = (unsigned*)(ws + off); off += (size_t)128 * 16 * 4;
    unsigned* tkt    = (unsigned*)(ws + off); off += (size_t)8 * 16 * 4;
    unsigned* bar    = (unsigned*)(ws + off); off += (size_t)BAR_WORDS * 4;
    const size_t zbytes = (size_t)((ws + off) - zbase);
    float* h1l = (float*)(ws + off); off += (size_t)HSLOT * 4;
    float* h1u = (float*)(ws + off); off += (size_t)HSLOT * 4;

    hipMemsetAsync(zbase, 0, zbytes, stream);

    {
        const dim3 pgrid(G4 / 32, KTOT / 32);
        prep_weights_kernel<<<pgrid, 256, 0, stream>>>(w_ih0, w_hh0, Wt0);
        prep_weights_kernel<<<pgrid, 256, 0, stream>>>(w_ih1, w_hh1, Wt1);
    }

    frontend_kernel<<<(BATCH * NF) / 8, 512, 0, stream>>>(
        input_lb, input_ub, mtx1, mtx2, lin1_w, lin1_b, Xc, Xr);

    lstm_persistent<<<NBLK, 256, 0, stream>>>(
        Xc, Xr, Wt0, Wt1, b0, b1,
        RingC, RingR,
        L0c0, L0r0, L0c1, L0r1,
        L1c0, L1r0, L1c1, L1r1,
        h1l, h1u, bar, tkt, lflags, cflags);

    final_kernel<<<BATCH, 64, 0, stream>>>(h1l, h1u, lin2_w, lin2_b, out);
}

// Round 12
// 3967.541 us; speedup vs baseline: 1.2681x; 1.2681x over previous
//
#include <hip/hip_runtime.h>
#include <hip/hip_bf16.h>
#include <math.h>

#define BATCH 128
#define LEN   64000
#define FS    256
#define STEPS 200
#define NFILT 64
#define HID   512
#define HID2  512
#define NOUT  10
#define NF    320
#define G4    2048
#define KTOT  1024
#define NBLK  256
#define HSLOT (BATCH * HID2)

typedef __bf16  bf16x8 __attribute__((ext_vector_type(8)));
typedef float   f32x4  __attribute__((ext_vector_type(4)));
typedef __hip_bfloat16 hbf;

// gbar region word layout (stride-16 lines)
#define ARV(b)  (128 + (b) * 16)
#define REL_(i) (128 + 4096 + (i) * 16)
#define BAR_WORDS (128 + 4096 + 128)

// ---------------------------------------------------------------------------
__device__ __forceinline__ float fsig(float x) { return 1.f / (1.f + __expf(-x)); }
__device__ __forceinline__ float ftanh(float x) { return 1.f - 2.f / (__expf(2.f * x) + 1.f); }
__device__ __forceinline__ void imulf_(float al, float au, float bl, float bu,
                                       float& lo, float& hi) {
    const float p1 = al * bl, p2 = al * bu, p3 = au * bl, p4 = au * bu;
    lo = fminf(fminf(p1, p2), fminf(p3, p4));
    hi = fmaxf(fmaxf(p1, p2), fmaxf(p3, p4));
}

// ---- agent-scope ops (device-coherent point); R9-proven ------------------
__device__ __forceinline__ bf16x8 loadA16_agent(const hbf* p) {
    union { unsigned long long u[2]; bf16x8 v; } t;
    unsigned long long* q = (unsigned long long*)p;
    t.u[0] = __hip_atomic_load(q,     __ATOMIC_RELAXED, __HIP_MEMORY_SCOPE_AGENT);
    t.u[1] = __hip_atomic_load(q + 1, __ATOMIC_RELAXED, __HIP_MEMORY_SCOPE_AGENT);
    return t.v;
}
__device__ __forceinline__ void storeH_agent(hbf* p, float v) {
    const __hip_bfloat16 h = __float2bfloat16(v);
    __hip_atomic_store((unsigned short*)p, *(const unsigned short*)&h,
                       __ATOMIC_RELAXED, __HIP_MEMORY_SCOPE_AGENT);
}
__device__ __forceinline__ unsigned ld_flag(const unsigned* p) {
    return __hip_atomic_load(p, __ATOMIC_RELAXED, __HIP_MEMORY_SCOPE_AGENT);
}
__device__ __forceinline__ void st_flag(unsigned* p, unsigned v) {
    __hip_atomic_store(p, v, __ATOMIC_RELAXED, __HIP_MEMORY_SCOPE_AGENT);
}

// ---------------------------------------------------------------------------
// Frontend (unchanged, verified)
// ---------------------------------------------------------------------------
__global__ __launch_bounds__(512) void frontend_kernel(
    const float* __restrict__ lb, const float* __restrict__ ub,
    const float* __restrict__ mtx1, const float* __restrict__ mtx2,
    const float* __restrict__ lin1_w, const float* __restrict__ lin1_b,
    hbf* __restrict__ Xc, hbf* __restrict__ Xr)
{
    const int tid  = threadIdx.x;
    const int r    = tid >> 6;
    const int lane = tid & 63;
    const int rowid = blockIdx.x * 8 + r;
    const int f = rowid % NF;
    const int b = rowid / NF;

    __shared__ float sc[8][FS], sr[8][FS];
    __shared__ float s2c[8][FS + 2], s2r[8][FS + 2];
    __shared__ float s3c[8][NFILT], s3r[8][NFILT];

    for (int i = lane; i < FS; i += 64) {
        const int pos = f * STEPS + i;
        float l = 0.f, u = 0.f;
        if (pos < LEN) {
            l = lb[(size_t)b * LEN + pos];
            u = ub[(size_t)b * LEN + pos];
        }
        sc[r][i] = 0.5f * (l + u);
        sr[r][i] = 0.5f * (u - l);
    }
    __syncthreads();

    for (int j = lane; j < FS + 2; j += 64) {
        float oc = 0.f, orr = 0.f;
#pragma unroll 4
        for (int i = 0; i < FS; ++i) {
            const float w = mtx1[i * (FS + 2) + j];
            oc  = fmaf(sc[r][i], w, oc);
            orr = fmaf(sr[r][i], fabsf(w), orr);
        }
        const float l1l = oc - orr, l1u = oc + orr;
        const float a = l1l * l1l, bb = l1u * l1u;
        const float squ = fmaxf(a, bb);
        const float sql = (l1l <= 0.f && l1u >= 0.f) ? 0.f : fminf(a, bb);
        s2c[r][j] = 0.5f * (sql + squ);
        s2r[r][j] = 0.5f * (squ - sql);
    }
    __syncthreads();

    {
        const int j = lane;
        float oc = 1e-10f, orr = 0.f;
#pragma unroll 4
        for (int i = 0; i < FS + 2; ++i) {
            const float w = mtx2[i * NFILT + j];
            oc  = fmaf(s2c[r][i], w, oc);
            orr = fmaf(s2r[r][i], fabsf(w), orr);
        }
        const float lgl = logf(oc - orr);
        const float lgu = logf(oc + orr);
        s3c[r][j] = 0.5f * (lgl + lgu);
        s3r[r][j] = 0.5f * (lgu - lgl);
    }
    __syncthreads();

    for (int j = lane; j < HID; j += 64) {
        float oc = lin1_b[j], orr = 0.f;
#pragma unroll 4
        for (int i = 0; i < NFILT; ++i) {
            const float w = lin1_w[i * HID + j];
            oc  = fmaf(s3c[r][i], w, oc);
            orr = fmaf(s3r[r][i], fabsf(w), orr);
        }
        const float n1l = oc - orr, n1u = oc + orr;
        const float rl = fmaxf(n1l, 0.f), ru = fmaxf(n1u, 0.f);
        const size_t o = ((size_t)f * BATCH + b) * HID + j;
        Xc[o] = __float2bfloat16(0.5f * (rl + ru));
        Xr[o] = __float2bfloat16(0.5f * (ru - rl));
    }
}

// ---------------------------------------------------------------------------
__global__ __launch_bounds__(256) void prep_weights_kernel(
    const float* __restrict__ wih, const float* __restrict__ whh,
    hbf* __restrict__ Wt)
{
    __shared__ float tile[32][33];
    const int n0 = blockIdx.x * 32;
    const int k0 = blockIdx.y * 32;
    const int tx = threadIdx.x & 31;
    const int ty = threadIdx.x >> 5;

    for (int r = ty; r < 32; r += 8) {
        const int k = k0 + r;
        const float* src = (k < HID) ? (wih + (size_t)k * G4)
                                     : (whh + (size_t)(k - HID) * G4);
        tile[r][tx] = src[n0 + tx];
    }
    __syncthreads();
    for (int r = ty; r < 32; r += 8) {
        const int n = n0 + r;
        Wt[(size_t)n * KTOT + k0 + tx] = __float2bfloat16(tile[tx][r]);
    }
}

// ---------------------------------------------------------------------------
// One-time global barrier for registration (R7-proven).
// ---------------------------------------------------------------------------
__device__ __forceinline__ void gbar(unsigned* bar, unsigned gen,
                                     int bid, int tid) {
    __builtin_amdgcn_s_waitcnt(0);
    __syncthreads();
    if (bid == 0) {
        if (tid != 0) {
            while (ld_flag(&bar[ARV(tid)]) < gen)
                __builtin_amdgcn_s_sleep(1);
        }
        __syncthreads();
        if (tid < 8) st_flag(&bar[REL_(tid)], gen);
    } else {
        if (tid == 0) {
            st_flag(&bar[ARV(bid)], gen);
            while (ld_flag(&bar[REL_(bid & 7)]) < gen)
                __builtin_amdgcn_s_sleep(4);
        }
        asm volatile("" ::: "memory");
    }
    __syncthreads();
}

// ---------------------------------------------------------------------------
__device__ __forceinline__ void cell_elem(
    const float C[4], const float R[4], const float bs[4],
    float& cl_r, float& cu_r, float& nhl, float& nhu)
{
    float gl[4], gu[4];
#pragma unroll
    for (int g = 0; g < 4; ++g) {
        gl[g] = C[g] - R[g] + bs[g];
        gu[g] = C[g] + R[g] + bs[g];
    }
    const float il = fsig(gl[0]), iu = fsig(gu[0]);
    const float fl = fsig(gl[1]), fu = fsig(gu[1]);
    const float ggl = ftanh(gl[2]), ggu = ftanh(gu[2]);
    const float ol = fsig(gl[3]), ou = fsig(gu[3]);

    float fcl, fcu, igl, igu;
    imulf_(fl, fu, cl_r, cu_r, fcl, fcu);
    imulf_(il, iu, ggl, ggu, igl, igu);
    const float ncl = fcl + igl, ncu = fcu + igu;
    cl_r = ncl; cu_r = ncu;
    imulf_(ol, ou, ftanh(ncl), ftanh(ncu), nhl, nhu);
}

// GEMM over one K-half from LDS weights; MASKED is a literal 0/1.
#define GEMM_HALF(KBASE, MASKED)                                               \
    _Pragma("unroll")                                                          \
    for (int kk = 0; kk < 16; ++kk) {                                          \
        const int KK = (KBASE) + kk;                                           \
        _Pragma("unroll")                                                      \
        for (int g = 0; g < 4; ++g) {                                          \
            union { bf16x8 v; unsigned u[4]; } t2;                             \
            t2.v = *(const bf16x8*)&Wlds[(size_t)(((g << 5) | KK) * 64 + lane) * 8]; \
            if (MASKED) {                                                      \
                t2.u[0] &= 0x7FFF7FFFu; t2.u[1] &= 0x7FFF7FFFu;                \
                t2.u[2] &= 0x7FFF7FFFu; t2.u[3] &= 0x7FFF7FFFu;                \
            }                                                                  \
            acc[g] = __builtin_amdgcn_mfma_f32_16x16x32_bf16(af[kk], t2.v, acc[g], 0, 0, 0); \
        }                                                                      \
    }

#define LOADA16(PTR)                                                           \
    _Pragma("unroll")                                                          \
    for (int i = 0; i < 16; ++i) af[i] = *(const bf16x8*)((PTR) + 32 * i);

// ---------------------------------------------------------------------------
// Persistent LSTM — fence-free cached H exchange.
// L0 writes H straight into a full-history ring via AGENT stores (data lands
// at the device coherent point). Consumers (own group at t-1, L1 group at t)
// use PLAIN CACHED loads: each ring address is written exactly once per
// launch and read only after its flag, so no stale cache line can exist —
// no fences needed, and the XCD's L2 absorbs the 32x intra-group read
// amplification. L1's own H keeps the R9-proven agent-load ping-pong.
// Flags: relaxed agent atomics; L1 polls L0's lflags >= t+1 directly.
// ---------------------------------------------------------------------------
__global__ __launch_bounds__(256, 1) void lstm_persistent(
    const hbf* __restrict__ Xc, const hbf* __restrict__ Xr,
    const hbf* __restrict__ Wt0, const hbf* __restrict__ Wt1,
    const float* __restrict__ b0, const float* __restrict__ b1,
    hbf* __restrict__ Ring0C, hbf* __restrict__ Ring0R,   // NF+1 slots (slot NF = zeros)
    hbf* __restrict__ H1c0, hbf* __restrict__ H1r0,
    hbf* __restrict__ H1c1, hbf* __restrict__ H1r1,
    float* __restrict__ h1l, float* __restrict__ h1u,
    unsigned* __restrict__ bar, unsigned* __restrict__ tkt,
    unsigned* __restrict__ lflags)
{
    const int tid = threadIdx.x;
    const int bid = blockIdx.x;

    __shared__ unsigned s_info, s_map;
    __shared__ int s_fast;
    __shared__ hbf   Wlds[4 * 32 * 64 * 8];      // 128 KB [g][KK][lane][8]
    __shared__ float red[2][2][4][64][4];        // 16 KB [op][mh][g][lane][reg]

    // ---- registration: physical XCD + ticket (locality only; always correct) ----
    if (tid == 0) {
        unsigned xcc;
        asm volatile("s_getreg_b32 %0, hwreg(HW_REG_XCC_ID)" : "=s"(xcc));
        xcc &= 7u;
        const unsigned slot = __hip_atomic_fetch_add(
            &tkt[xcc * 16], 1u, __ATOMIC_RELAXED, __HIP_MEMORY_SCOPE_AGENT);
        s_info = (xcc << 16) | slot;
    }
    gbar(bar, 1, bid, tid);
    if (tid == 0) {
        unsigned cnt[8]; bool ok = true;
        for (int y = 0; y < 8; ++y) {
            cnt[y] = ld_flag(&tkt[y * 16]);
            ok = ok && (cnt[y] == 32u);
        }
        const unsigned xcc = s_info >> 16, slot = s_info & 0xffffu;
        unsigned rank;
        if (ok) rank = xcc * 32u + slot;
        else { rank = slot; for (unsigned y = 0; y < xcc; ++y) rank += cnt[y]; }
        s_map = rank; s_fast = ok ? 1 : 0;
    }
    __syncthreads();

    const unsigned rank = s_map;
    int layer, mgrp, jslot;
    if (s_fast) { layer = (rank >> 5) & 1; mgrp = rank >> 6; jslot = rank & 31; }
    else        { layer = rank >> 7; mgrp = (rank >> 5) & 3; jslot = rank & 31; }
    const int m0 = mgrp * 32;
    const int j0 = jslot * 16;
    const int lfbase  = layer * 128 + mgrp * 32;   // own group's flag lines
    const int l0fbase = mgrp * 32;                 // partner L0 group's lines
    const int myLf = lfbase + jslot;

    // ---- stage weight slice into LDS ----
    {
        const hbf* Wt = layer ? Wt1 : Wt0;
        for (int c = tid; c < 8192; c += 256) {
            const int g  = c >> 11;
            const int kk = (c >> 6) & 31;
            const int l6 = c & 63;
            const int n  = g * HID2 + j0 + (l6 & 15);
            const int k  = kk * 32 + (l6 >> 4) * 8;
            *(ulonglong2*)&Wlds[(size_t)c * 8] =
                *(const ulonglong2*)(Wt + (size_t)n * KTOT + k);
        }
    }

    const int w    = tid >> 6;
    const int lane = tid & 63;
    const int op   = w & 1;                  // 0 center, 1 radius
    const int mh   = w >> 1;                 // m-half
    const int rc   = lane & 15;
    const int gk   = lane >> 4;
    const int aoff = (m0 + mh * 16 + rc) * 512 + 8 * gk;

    hbf* H1cb[2] = { H1c0, H1c1 };
    hbf* H1rb[2] = { H1r0, H1r1 };

    // cell-phase constants
    const int mm  = tid >> 4;
    const int cj  = tid & 15;
    const int ll  = ((mm >> 2) << 4) | cj;
    const int rr  = mm & 3;
    const int idx0 = (m0 + mm) * HID2 + j0 + cj;
    const int idx1 = idx0 + 16 * HID2;
    const float* bias = layer ? b1 : b0;
    float bs[4];
#pragma unroll
    for (int g = 0; g < 4; ++g) bs[g] = bias[g * HID2 + j0 + cj];

    float cAl = 0.f, cAu = 0.f, cBl = 0.f, cBu = 0.f;

    __syncthreads();                         // Wlds ready

    for (int t = 0; t < NF; ++t) {
        const int wslot = t & 1, rslot = wslot ^ 1;
        f32x4 acc[4] = {f32x4{0,0,0,0}, f32x4{0,0,0,0},
                        f32x4{0,0,0,0}, f32x4{0,0,0,0}};
        bf16x8 af[16];

        if (layer == 0) {
            // x-half on X[t] (plain, pre-poll)
            {
                const hbf* p = (op ? Xr : Xc) + (size_t)t * HSLOT + aoff;
                LOADA16(p)
                if (op) { GEMM_HALF(0, 1) } else { GEMM_HALF(0, 0) }
            }
            // poll own group >= t (slot t-1 published)
            if (tid < 64) {
                const unsigned* p = &lflags[(lfbase + (tid & 31)) * 16];
                for (;;) {
                    const unsigned v = ld_flag(p);
                    if (__all((int)v >= t)) break;
                    __builtin_amdgcn_s_sleep(1);
                }
            }
            __syncthreads();
            // h-half on Ring0[t-1] — PLAIN cached load (fresh address)
            {
                const int pt = (t == 0) ? NF : t - 1;
                const hbf* p = (op ? Ring0R : Ring0C) + (size_t)pt * HSLOT + aoff;
                LOADA16(p)
                if (op) { GEMM_HALF(16, 1) } else { GEMM_HALF(16, 0) }
            }
        } else {
            // combined poll: own >= t (lanes 0..31), L0 partner >= t+1 (lanes 32..63)
            if (tid < 64) {
                const int fb  = (tid < 32) ? (lfbase + tid) : (l0fbase + (tid - 32));
                const int tgt = (tid < 32) ? t : (t + 1);
                const unsigned* p = &lflags[fb * 16];
                for (;;) {
                    const unsigned v = ld_flag(p);
                    if (__all((int)v >= tgt)) break;
                    __builtin_amdgcn_s_sleep(1);
                }
            }
            __syncthreads();
            // h-half on H1 ping-pong — agent loads (R9-proven)
            {
                const hbf* p = (op ? H1rb[rslot] : H1cb[rslot]) + aoff;
#pragma unroll
                for (int i = 0; i < 16; ++i) af[i] = loadA16_agent(p + 32 * i);
                if (op) { GEMM_HALF(16, 1) } else { GEMM_HALF(16, 0) }
            }
            // x-half on Ring0[t] — PLAIN cached load (fresh address)
            {
                const hbf* p = (op ? Ring0R : Ring0C) + (size_t)t * HSLOT + aoff;
                LOADA16(p)
                if (op) { GEMM_HALF(0, 1) } else { GEMM_HALF(0, 0) }
            }
        }

        // ---- reduce C/R across waves via LDS ----
#pragma unroll
        for (int g = 0; g < 4; ++g)
            *((f32x4*)&red[op][mh][g][lane][0]) = acc[g];
        __syncthreads();

        // ---- cell: 2 elements per thread ----
        {
            float C0[4], R0[4], C1[4], R1[4];
#pragma unroll
            for (int g = 0; g < 4; ++g) {
                C0[g] = red[0][0][g][ll][rr];
                R0[g] = red[1][0][g][ll][rr];
                C1[g] = red[0][1][g][ll][rr];
                R1[g] = red[1][1][g][ll][rr];
            }
            const bool writeF = (layer == 1) && (t == NF - 1);

            float nhl, nhu;
            cell_elem(C0, R0, bs, cAl, cAu, nhl, nhu);
            float hc = 0.5f * (nhl + nhu), hr = 0.5f * (nhu - nhl);
            if (layer == 0) {
                const size_t rb = (size_t)t * HSLOT;
                storeH_agent(&Ring0C[rb + idx0], hc);
                storeH_agent(&Ring0R[rb + idx0], hr);
            } else {
                storeH_agent(&H1cb[wslot][idx0], hc);
                storeH_agent(&H1rb[wslot][idx0], hr);
            }
            if (writeF) { h1l[idx0] = nhl; h1u[idx0] = nhu; }

            cell_elem(C1, R1, bs, cBl, cBu, nhl, nhu);
            hc = 0.5f * (nhl + nhu); hr = 0.5f * (nhu - nhl);
            if (layer == 0) {
                const size_t rb = (size_t)t * HSLOT;
                storeH_agent(&Ring0C[rb + idx1], hc);
                storeH_agent(&Ring0R[rb + idx1], hr);
            } else {
                storeH_agent(&H1cb[wslot][idx1], hc);
                storeH_agent(&H1rb[wslot][idx1], hr);
            }
            if (writeF) { h1l[idx1] = nhl; h1u[idx1] = nhu; }
        }

        // ---- arrive: drain agent stores, publish flag ----
        __builtin_amdgcn_s_waitcnt(0);
        __syncthreads();
        if (tid == 0)
            st_flag(&lflags[myLf * 16], (unsigned)(t + 1));
    }
}

// ---------------------------------------------------------------------------
__global__ __launch_bounds__(64) void final_kernel(
    const float* __restrict__ h1l, const float* __restrict__ h1u,
    const float* __restrict__ w, const float* __restrict__ bias,
    float* __restrict__ out)
{
    const int b = blockIdx.x;
    const int j = threadIdx.x;
    if (j < NOUT) {
        float oc = bias[j], orr = 0.f;
        for (int i = 0; i < HID2; ++i) {
            const float lo = h1l[(size_t)b * HID2 + i];
            const float hi = h1u[(size_t)b * HID2 + i];
            const float wv = w[i * NOUT + j];
            oc  = fmaf(0.5f * (lo + hi), wv, oc);
            orr = fmaf(0.5f * (hi - lo), fabsf(wv), orr);
        }
        out[b * NOUT + j] = oc - orr;
        out[BATCH * NOUT + b * NOUT + j] = oc + orr;
    }
}

// ---------------------------------------------------------------------------
extern "C" void kernel_launch(void* const* d_in, const int* in_sizes, int n_in,
                              void* d_out, int out_size, void* d_ws, size_t ws_size,
                              hipStream_t stream)
{
    const float* input_lb = (const float*)d_in[0];
    const float* input_ub = (const float*)d_in[1];
    const float* mtx1     = (const float*)d_in[2];
    const float* mtx2     = (const float*)d_in[3];
    const float* lin1_w   = (const float*)d_in[4];
    const float* lin1_b   = (const float*)d_in[5];
    const float* w_ih0    = (const float*)d_in[6];
    const float* w_hh0    = (const float*)d_in[7];
    const float* b0       = (const float*)d_in[8];
    const float* w_ih1    = (const float*)d_in[9];
    const float* w_hh1    = (const float*)d_in[10];
    const float* b1       = (const float*)d_in[11];
    const float* lin2_w   = (const float*)d_in[12];
    const float* lin2_b   = (const float*)d_in[13];
    float* out = (float*)d_out;

    char* ws = (char*)d_ws;
    size_t off = 0;
    hbf* Xc = (hbf*)(ws + off); off += (size_t)NF * HSLOT * 2;
    hbf* Xr = (hbf*)(ws + off); off += (size_t)NF * HSLOT * 2;
    hbf* Wt0 = (hbf*)(ws + off); off += (size_t)G4 * KTOT * 2;
    hbf* Wt1 = (hbf*)(ws + off); off += (size_t)G4 * KTOT * 2;
    hbf* Ring0C = (hbf*)(ws + off); off += (size_t)(NF + 1) * HSLOT * 2;
    hbf* Ring0R = (hbf*)(ws + off); off += (size_t)(NF + 1) * HSLOT * 2;

    // zeroed-every-launch region
    char* zbase = ws + off;
    hbf* H1c0 = (hbf*)(ws + off); off += (size_t)HSLOT * 2;
    hbf* H1r0 = (hbf*)(ws + off); off += (size_t)HSLOT * 2;
    hbf* H1c1 = (hbf*)(ws + off); off += (size_t)HSLOT * 2;
    hbf* H1r1 = (hbf*)(ws + off); off += (size_t)HSLOT * 2;
    unsigned* lflags = (unsigned*)(ws + off); off += (size_t)256 * 16 * 4;
    unsigned* tkt    = (unsigned*)(ws + off); off += (size_t)8 * 16 * 4;
    unsigned* bar    = (unsigned*)(ws + off); off += (size_t)BAR_WORDS * 4;
    const size_t zbytes = (size_t)((ws + off) - zbase);
    float* h1l = (float*)(ws + off); off += (size_t)HSLOT * 4;
    float* h1u = (float*)(ws + off); off += (size_t)HSLOT * 4;

    hipMemsetAsync(zbase, 0, zbytes, stream);
    // ring zero slots (slot NF) for t=0 h-reads
    hipMemsetAsync(Ring0C + (size_t)NF * HSLOT, 0, (size_t)HSLOT * 2, stream);
    hipMemsetAsync(Ring0R + (size_t)NF * HSLOT, 0, (size_t)HSLOT * 2, stream);

    {
        const dim3 pgrid(G4 / 32, KTOT / 32);
        prep_weights_kernel<<<pgrid, 256, 0, stream>>>(w_ih0, w_hh0, Wt0);
        prep_weights_kernel<<<pgrid, 256, 0, stream>>>(w_ih1, w_hh1, Wt1);
    }

    frontend_kernel<<<(BATCH * NF) / 8, 512, 0, stream>>>(
        input_lb, input_ub, mtx1, mtx2, lin1_w, lin1_b, Xc, Xr);

    lstm_persistent<<<NBLK, 256, 0, stream>>>(
        Xc, Xr, Wt0, Wt1, b0, b1,
        Ring0C, Ring0R,
        H1c0, H1r0, H1c1, H1r1,
        h1l, h1u, bar, tkt, lflags);

    final_kernel<<<BATCH, 64, 0, stream>>>(h1l, h1u, lin2_w, lin2_b, out);
}

// Round 13
// 3399.424 us; speedup vs baseline: 1.4800x; 1.1671x over previous
//
#include <hip/hip_runtime.h>
#include <hip/hip_bf16.h>
#include <math.h>

#define BATCH 128
#define LEN   64000
#define FS    256
#define STEPS 200
#define NFILT 64
#define HID   512
#define HID2  512
#define NOUT  10
#define NF    320
#define G4    2048
#define KTOT  1024
#define NBLK  256
#define HSLOT (BATCH * HID2)

typedef __bf16  bf16x8 __attribute__((ext_vector_type(8)));
typedef float   f32x4  __attribute__((ext_vector_type(4)));
typedef __hip_bfloat16 hbf;

// gbar region word layout (stride-16 lines)
#define ARV(b)  (128 + (b) * 16)
#define REL_(i) (128 + 4096 + (i) * 16)
#define BAR_WORDS (128 + 4096 + 128)

// ---------------------------------------------------------------------------
__device__ __forceinline__ float fsig(float x) { return 1.f / (1.f + __expf(-x)); }
__device__ __forceinline__ float ftanh(float x) { return 1.f - 2.f / (__expf(2.f * x) + 1.f); }
__device__ __forceinline__ void imulf_(float al, float au, float bl, float bu,
                                       float& lo, float& hi) {
    const float p1 = al * bl, p2 = al * bu, p3 = au * bl, p4 = au * bu;
    lo = fminf(fminf(p1, p2), fminf(p3, p4));
    hi = fmaxf(fmaxf(p1, p2), fmaxf(p3, p4));
}

// ---- agent-scope ops (device-coherent point); R9/R12-proven --------------
__device__ __forceinline__ bf16x8 loadA16_agent(const hbf* p) {
    union { unsigned long long u[2]; bf16x8 v; } t;
    unsigned long long* q = (unsigned long long*)p;
    t.u[0] = __hip_atomic_load(q,     __ATOMIC_RELAXED, __HIP_MEMORY_SCOPE_AGENT);
    t.u[1] = __hip_atomic_load(q + 1, __ATOMIC_RELAXED, __HIP_MEMORY_SCOPE_AGENT);
    return t.v;
}
__device__ __forceinline__ unsigned ld_flag(const unsigned* p) {
    return __hip_atomic_load(p, __ATOMIC_RELAXED, __HIP_MEMORY_SCOPE_AGENT);
}
__device__ __forceinline__ void st_flag(unsigned* p, unsigned v) {
    __hip_atomic_store(p, v, __ATOMIC_RELAXED, __HIP_MEMORY_SCOPE_AGENT);
}

// ---------------------------------------------------------------------------
// Frontend (unchanged, verified)
// ---------------------------------------------------------------------------
__global__ __launch_bounds__(512) void frontend_kernel(
    const float* __restrict__ lb, const float* __restrict__ ub,
    const float* __restrict__ mtx1, const float* __restrict__ mtx2,
    const float* __restrict__ lin1_w, const float* __restrict__ lin1_b,
    hbf* __restrict__ Xc, hbf* __restrict__ Xr)
{
    const int tid  = threadIdx.x;
    const int r    = tid >> 6;
    const int lane = tid & 63;
    const int rowid = blockIdx.x * 8 + r;
    const int f = rowid % NF;
    const int b = rowid / NF;

    __shared__ float sc[8][FS], sr[8][FS];
    __shared__ float s2c[8][FS + 2], s2r[8][FS + 2];
    __shared__ float s3c[8][NFILT], s3r[8][NFILT];

    for (int i = lane; i < FS; i += 64) {
        const int pos = f * STEPS + i;
        float l = 0.f, u = 0.f;
        if (pos < LEN) {
            l = lb[(size_t)b * LEN + pos];
            u = ub[(size_t)b * LEN + pos];
        }
        sc[r][i] = 0.5f * (l + u);
        sr[r][i] = 0.5f * (u - l);
    }
    __syncthreads();

    for (int j = lane; j < FS + 2; j += 64) {
        float oc = 0.f, orr = 0.f;
#pragma unroll 4
        for (int i = 0; i < FS; ++i) {
            const float w = mtx1[i * (FS + 2) + j];
            oc  = fmaf(sc[r][i], w, oc);
            orr = fmaf(sr[r][i], fabsf(w), orr);
        }
        const float l1l = oc - orr, l1u = oc + orr;
        const float a = l1l * l1l, bb = l1u * l1u;
        const float squ = fmaxf(a, bb);
        const float sql = (l1l <= 0.f && l1u >= 0.f) ? 0.f : fminf(a, bb);
        s2c[r][j] = 0.5f * (sql + squ);
        s2r[r][j] = 0.5f * (squ - sql);
    }
    __syncthreads();

    {
        const int j = lane;
        float oc = 1e-10f, orr = 0.f;
#pragma unroll 4
        for (int i = 0; i < FS + 2; ++i) {
            const float w = mtx2[i * NFILT + j];
            oc  = fmaf(s2c[r][i], w, oc);
            orr = fmaf(s2r[r][i], fabsf(w), orr);
        }
        const float lgl = logf(oc - orr);
        const float lgu = logf(oc + orr);
        s3c[r][j] = 0.5f * (lgl + lgu);
        s3r[r][j] = 0.5f * (lgu - lgl);
    }
    __syncthreads();

    for (int j = lane; j < HID; j += 64) {
        float oc = lin1_b[j], orr = 0.f;
#pragma unroll 4
        for (int i = 0; i < NFILT; ++i) {
            const float w = lin1_w[i * HID + j];
            oc  = fmaf(s3c[r][i], w, oc);
            orr = fmaf(s3r[r][i], fabsf(w), orr);
        }
        const float n1l = oc - orr, n1u = oc + orr;
        const float rl = fmaxf(n1l, 0.f), ru = fmaxf(n1u, 0.f);
        const size_t o = ((size_t)f * BATCH + b) * HID + j;
        Xc[o] = __float2bfloat16(0.5f * (rl + ru));
        Xr[o] = __float2bfloat16(0.5f * (ru - rl));
    }
}

// ---------------------------------------------------------------------------
__global__ __launch_bounds__(256) void prep_weights_kernel(
    const float* __restrict__ wih, const float* __restrict__ whh,
    hbf* __restrict__ Wt)
{
    __shared__ float tile[32][33];
    const int n0 = blockIdx.x * 32;
    const int k0 = blockIdx.y * 32;
    const int tx = threadIdx.x & 31;
    const int ty = threadIdx.x >> 5;

    for (int r = ty; r < 32; r += 8) {
        const int k = k0 + r;
        const float* src = (k < HID) ? (wih + (size_t)k * G4)
                                     : (whh + (size_t)(k - HID) * G4);
        tile[r][tx] = src[n0 + tx];
    }
    __syncthreads();
    for (int r = ty; r < 32; r += 8) {
        const int n = n0 + r;
        Wt[(size_t)n * KTOT + k0 + tx] = __float2bfloat16(tile[tx][r]);
    }
}

// ---------------------------------------------------------------------------
// One-time global barrier for registration (R7-proven).
// ---------------------------------------------------------------------------
__device__ __forceinline__ void gbar(unsigned* bar, unsigned gen,
                                     int bid, int tid) {
    __builtin_amdgcn_s_waitcnt(0);
    __syncthreads();
    if (bid == 0) {
        if (tid != 0) {
            while (ld_flag(&bar[ARV(tid)]) < gen)
                __builtin_amdgcn_s_sleep(1);
        }
        __syncthreads();
        if (tid < 8) st_flag(&bar[REL_(tid)], gen);
    } else {
        if (tid == 0) {
            st_flag(&bar[ARV(bid)], gen);
            while (ld_flag(&bar[REL_(bid & 7)]) < gen)
                __builtin_amdgcn_s_sleep(4);
        }
        asm volatile("" ::: "memory");
    }
    __syncthreads();
}

// ---------------------------------------------------------------------------
__device__ __forceinline__ void cell_elem(
    const float C[4], const float R[4], const float bs[4],
    float& cl_r, float& cu_r, float& nhl, float& nhu)
{
    float gl[4], gu[4];
#pragma unroll
    for (int g = 0; g < 4; ++g) {
        gl[g] = C[g] - R[g] + bs[g];
        gu[g] = C[g] + R[g] + bs[g];
    }
    const float il = fsig(gl[0]), iu = fsig(gu[0]);
    const float fl = fsig(gl[1]), fu = fsig(gu[1]);
    const float ggl = ftanh(gl[2]), ggu = ftanh(gu[2]);
    const float ol = fsig(gl[3]), ou = fsig(gu[3]);

    float fcl, fcu, igl, igu;
    imulf_(fl, fu, cl_r, cu_r, fcl, fcu);
    imulf_(il, iu, ggl, ggu, igl, igu);
    const float ncl = fcl + igl, ncu = fcu + igu;
    cl_r = ncl; cu_r = ncu;
    imulf_(ol, ou, ftanh(ncl), ftanh(ncu), nhl, nhu);
}

// GEMM over one K-half from LDS weights; MASKED is a literal 0/1.
#define GEMM_HALF(KBASE, MASKED)                                               \
    _Pragma("unroll")                                                          \
    for (int kk = 0; kk < 16; ++kk) {                                          \
        const int KK = (KBASE) + kk;                                           \
        _Pragma("unroll")                                                      \
        for (int g = 0; g < 4; ++g) {                                          \
            union { bf16x8 v; unsigned u[4]; } t2;                             \
            t2.v = *(const bf16x8*)&Wlds[(size_t)(((g << 5) | KK) * 64 + lane) * 8]; \
            if (MASKED) {                                                      \
                t2.u[0] &= 0x7FFF7FFFu; t2.u[1] &= 0x7FFF7FFFu;                \
                t2.u[2] &= 0x7FFF7FFFu; t2.u[3] &= 0x7FFF7FFFu;                \
            }                                                                  \
            acc[g] = __builtin_amdgcn_mfma_f32_16x16x32_bf16(af[kk], t2.v, acc[g], 0, 0, 0); \
        }                                                                      \
    }

#define LOADA16(PTR)                                                           \
    _Pragma("unroll")                                                          \
    for (int i = 0; i < 16; ++i) af[i] = *(const bf16x8*)((PTR) + 32 * i);

#define POLL_GROUP(BASE, TGT)                                                  \
    if (tid < 64) {                                                            \
        const unsigned* pp = &lflags[((BASE) + (tid & 31)) * 16];              \
        for (;;) {                                                             \
            const unsigned v = ld_flag(pp);                                    \
            if (__all((int)v >= (TGT))) break;                                 \
            __builtin_amdgcn_s_sleep(1);                                       \
        }                                                                      \
    }                                                                          \
    __syncthreads();

// ---------------------------------------------------------------------------
// Persistent LSTM — fence-free cached H exchange, coalesced publication.
// L0 publishes H0[t] into Ring0 (write-once addresses, agent u64 stores via
// LDS staging); consumers use plain cached loads after flag-gating. In the
// XCD-verified fast path, L1 recycles the X buffers as its own H-ring
// (X[t] is provably consumed by L0 before L1 writes H1[t] there) — giving
// L1 the same plain-cached h-path. Fallback (unbalanced dispatch): R12's
// agent ping-pong for L1's H. L1's polls are split so its h-GEMM overlaps
// the wait on L0. Flags: relaxed agent atomics, one line per block.
// ---------------------------------------------------------------------------
__global__ __launch_bounds__(256, 1) void lstm_persistent(
    const hbf* Xc, const hbf* Xr,                       // NO restrict: aliased w/ Ring1
    hbf* Ring1C, hbf* Ring1R,                           // = Xc, Xr (fast path)
    const hbf* __restrict__ Wt0, const hbf* __restrict__ Wt1,
    const float* __restrict__ b0, const float* __restrict__ b1,
    hbf* __restrict__ Ring0C, hbf* __restrict__ Ring0R, // NF+1 slots (slot NF = zeros)
    const hbf* __restrict__ Zbuf,                       // HSLOT zeros
    hbf* __restrict__ H1c0, hbf* __restrict__ H1r0,
    hbf* __restrict__ H1c1, hbf* __restrict__ H1r1,
    float* __restrict__ h1l, float* __restrict__ h1u,
    unsigned* __restrict__ bar, unsigned* __restrict__ tkt,
    unsigned* __restrict__ lflags)
{
    const int tid = threadIdx.x;
    const int bid = blockIdx.x;

    __shared__ unsigned s_info, s_map;
    __shared__ int s_fast;
    __shared__ hbf   Wlds[4 * 32 * 64 * 8];      // 128 KB [g][KK][lane][8]
    __shared__ float red[2][2][4][64][4];        // 16 KB [op][mh][g][lane][reg]
    __shared__ unsigned short houtC[32][16], houtR[32][16];   // 2 KB staging

    // ---- registration: physical XCD + ticket (locality; always correct) ----
    if (tid == 0) {
        unsigned xcc;
        asm volatile("s_getreg_b32 %0, hwreg(HW_REG_XCC_ID)" : "=s"(xcc));
        xcc &= 7u;
        const unsigned slot = __hip_atomic_fetch_add(
            &tkt[xcc * 16], 1u, __ATOMIC_RELAXED, __HIP_MEMORY_SCOPE_AGENT);
        s_info = (xcc << 16) | slot;
    }
    gbar(bar, 1, bid, tid);
    if (tid == 0) {
        unsigned cnt[8]; bool ok = true;
        for (int y = 0; y < 8; ++y) {
            cnt[y] = ld_flag(&tkt[y * 16]);
            ok = ok && (cnt[y] == 32u);
        }
        const unsigned xcc = s_info >> 16, slot = s_info & 0xffffu;
        unsigned rank;
        if (ok) rank = xcc * 32u + slot;
        else { rank = slot; for (unsigned y = 0; y < xcc; ++y) rank += cnt[y]; }
        s_map = rank; s_fast = ok ? 1 : 0;
    }
    __syncthreads();

    const unsigned rank = s_map;
    const bool fast = (s_fast != 0);
    int layer, mgrp, jslot;
    if (fast) { layer = (rank >> 5) & 1; mgrp = rank >> 6; jslot = rank & 31; }
    else      { layer = rank >> 7; mgrp = (rank >> 5) & 3; jslot = rank & 31; }
    const int m0 = mgrp * 32;
    const int j0 = jslot * 16;
    const int lfbase  = layer * 128 + mgrp * 32;   // own group's flag lines
    const int l0fbase = mgrp * 32;                 // partner L0 group's lines
    const int myLf = lfbase + jslot;

    // ---- stage weight slice into LDS ----
    {
        const hbf* Wt = layer ? Wt1 : Wt0;
        for (int c = tid; c < 8192; c += 256) {
            const int g  = c >> 11;
            const int kk = (c >> 6) & 31;
            const int l6 = c & 63;
            const int n  = g * HID2 + j0 + (l6 & 15);
            const int k  = kk * 32 + (l6 >> 4) * 8;
            *(ulonglong2*)&Wlds[(size_t)c * 8] =
                *(const ulonglong2*)(Wt + (size_t)n * KTOT + k);
        }
    }

    const int w    = tid >> 6;
    const int lane = tid & 63;
    const int op   = w & 1;                  // 0 center, 1 radius
    const int mh   = w >> 1;                 // m-half
    const int rc   = lane & 15;
    const int gk   = lane >> 4;
    const int aoff = (m0 + mh * 16 + rc) * 512 + 8 * gk;

    hbf* H1cb[2] = { H1c0, H1c1 };
    hbf* H1rb[2] = { H1r0, H1r1 };

    // cell-phase constants
    const int mm  = tid >> 4;
    const int cj  = tid & 15;
    const int ll  = ((mm >> 2) << 4) | cj;
    const int rr  = mm & 3;
    const int idx0 = (m0 + mm) * HID2 + j0 + cj;
    const int idx1 = idx0 + 16 * HID2;
    const float* bias = layer ? b1 : b0;
    float bs[4];
#pragma unroll
    for (int g = 0; g < 4; ++g) bs[g] = bias[g * HID2 + j0 + cj];

    // coalesced-store constants (1 qword per thread)
    const int st_arr = tid >> 7;             // 0=C, 1=R
    const int st_row = (tid >> 2) & 31;
    const int st_q   = tid & 3;
    const size_t st_off = (size_t)(m0 + st_row) * 512 + j0 + st_q * 4;

    float cAl = 0.f, cAu = 0.f, cBl = 0.f, cBu = 0.f;

    __syncthreads();                         // Wlds ready

    for (int t = 0; t < NF; ++t) {
        const int wslot = t & 1, rslot = wslot ^ 1;
        f32x4 acc[4] = {f32x4{0,0,0,0}, f32x4{0,0,0,0},
                        f32x4{0,0,0,0}, f32x4{0,0,0,0}};
        bf16x8 af[16];

        if (layer == 0) {
            // x-half on X[t] (plain, pre-poll)
            {
                const hbf* p = (op ? Xr : Xc) + (size_t)t * HSLOT + aoff;
                LOADA16(p)
                if (op) { GEMM_HALF(0, 1) } else { GEMM_HALF(0, 0) }
            }
            POLL_GROUP(lfbase, t)
            // h-half on Ring0[t-1] — plain cached (fresh address)
            {
                const int pt = (t == 0) ? NF : t - 1;
                const hbf* p = (op ? Ring0R : Ring0C) + (size_t)pt * HSLOT + aoff;
                LOADA16(p)
                if (op) { GEMM_HALF(16, 1) } else { GEMM_HALF(16, 0) }
            }
        } else {
            POLL_GROUP(lfbase, t)
            // h-half on own H-ring — overlaps the wait on L0
            if (fast) {
                const hbf* p = (t == 0) ? (Zbuf + aoff)
                    : ((op ? (const hbf*)Ring1R : (const hbf*)Ring1C)
                       + (size_t)(t - 1) * HSLOT + aoff);
                LOADA16(p)
            } else {
                const hbf* p = (op ? H1rb[rslot] : H1cb[rslot]) + aoff;
#pragma unroll
                for (int i = 0; i < 16; ++i) af[i] = loadA16_agent(p + 32 * i);
            }
            if (op) { GEMM_HALF(16, 1) } else { GEMM_HALF(16, 0) }
            POLL_GROUP(l0fbase, t + 1)
            // x-half on Ring0[t] — plain cached (fresh address)
            {
                const hbf* p = (op ? Ring0R : Ring0C) + (size_t)t * HSLOT + aoff;
                LOADA16(p)
                if (op) { GEMM_HALF(0, 1) } else { GEMM_HALF(0, 0) }
            }
        }

        // ---- reduce C/R across waves via LDS ----
#pragma unroll
        for (int g = 0; g < 4; ++g)
            *((f32x4*)&red[op][mh][g][lane][0]) = acc[g];
        __syncthreads();

        // ---- cell: 2 elements per thread, stage into LDS ----
        {
            float C0[4], R0[4], C1[4], R1[4];
#pragma unroll
            for (int g = 0; g < 4; ++g) {
                C0[g] = red[0][0][g][ll][rr];
                R0[g] = red[1][0][g][ll][rr];
                C1[g] = red[0][1][g][ll][rr];
                R1[g] = red[1][1][g][ll][rr];
            }
            const bool writeF = (layer == 1) && (t == NF - 1);

            float nhl, nhu;
            cell_elem(C0, R0, bs, cAl, cAu, nhl, nhu);
            {
                const __hip_bfloat16 hc = __float2bfloat16(0.5f * (nhl + nhu));
                const __hip_bfloat16 hr = __float2bfloat16(0.5f * (nhu - nhl));
                houtC[mm][cj] = *(const unsigned short*)&hc;
                houtR[mm][cj] = *(const unsigned short*)&hr;
            }
            if (writeF) { h1l[idx0] = nhl; h1u[idx0] = nhu; }

            cell_elem(C1, R1, bs, cBl, cBu, nhl, nhu);
            {
                const __hip_bfloat16 hc = __float2bfloat16(0.5f * (nhl + nhu));
                const __hip_bfloat16 hr = __float2bfloat16(0.5f * (nhu - nhl));
                houtC[mm + 16][cj] = *(const unsigned short*)&hc;
                houtR[mm + 16][cj] = *(const unsigned short*)&hr;
            }
            if (writeF) { h1l[idx1] = nhl; h1u[idx1] = nhu; }
        }
        __syncthreads();

        // ---- coalesced publication: 1 agent u64 store per thread ----
        {
            hbf *dstC, *dstR;
            if (layer == 0) {
                dstC = Ring0C + (size_t)t * HSLOT;
                dstR = Ring0R + (size_t)t * HSLOT;
            } else if (fast) {
                dstC = Ring1C + (size_t)t * HSLOT;
                dstR = Ring1R + (size_t)t * HSLOT;
            } else {
                dstC = H1cb[wslot];
                dstR = H1rb[wslot];
            }
            const unsigned long long* src = (const unsigned long long*)
                &(st_arr ? houtR : houtC)[st_row][st_q * 4];
            unsigned long long* dst = (unsigned long long*)
                ((st_arr ? dstR : dstC) + st_off);
            __hip_atomic_store(dst, *src, __ATOMIC_RELAXED,
                               __HIP_MEMORY_SCOPE_AGENT);
        }

        // ---- arrive: drain, publish flag ----
        __builtin_amdgcn_s_waitcnt(0);
        __syncthreads();
        if (tid == 0)
            st_flag(&lflags[myLf * 16], (unsigned)(t + 1));
    }
}

// ---------------------------------------------------------------------------
__global__ __launch_bounds__(64) void final_kernel(
    const float* __restrict__ h1l, const float* __restrict__ h1u,
    const float* __restrict__ w, const float* __restrict__ bias,
    float* __restrict__ out)
{
    const int b = blockIdx.x;
    const int j = threadIdx.x;
    if (j < NOUT) {
        float oc = bias[j], orr = 0.f;
        for (int i = 0; i < HID2; ++i) {
            const float lo = h1l[(size_t)b * HID2 + i];
            const float hi = h1u[(size_t)b * HID2 + i];
            const float wv = w[i * NOUT + j];
            oc  = fmaf(0.5f * (lo + hi), wv, oc);
            orr = fmaf(0.5f * (hi - lo), fabsf(wv), orr);
        }
        out[b * NOUT + j] = oc - orr;
        out[BATCH * NOUT + b * NOUT + j] = oc + orr;
    }
}

// ---------------------------------------------------------------------------
extern "C" void kernel_launch(void* const* d_in, const int* in_sizes, int n_in,
                              void* d_out, int out_size, void* d_ws, size_t ws_size,
                              hipStream_t stream)
{
    const float* input_lb = (const float*)d_in[0];
    const float* input_ub = (const float*)d_in[1];
    const float* mtx1     = (const float*)d_in[2];
    const float* mtx2     = (const float*)d_in[3];
    const float* lin1_w   = (const float*)d_in[4];
    const float* lin1_b   = (const float*)d_in[5];
    const float* w_ih0    = (const float*)d_in[6];
    const float* w_hh0    = (const float*)d_in[7];
    const float* b0       = (const float*)d_in[8];
    const float* w_ih1    = (const float*)d_in[9];
    const float* w_hh1    = (const float*)d_in[10];
    const float* b1       = (const float*)d_in[11];
    const float* lin2_w   = (const float*)d_in[12];
    const float* lin2_b   = (const float*)d_in[13];
    float* out = (float*)d_out;

    char* ws = (char*)d_ws;
    size_t off = 0;
    hbf* Xc = (hbf*)(ws + off); off += (size_t)NF * HSLOT * 2;
    hbf* Xr = (hbf*)(ws + off); off += (size_t)NF * HSLOT * 2;
    hbf* Wt0 = (hbf*)(ws + off); off += (size_t)G4 * KTOT * 2;
    hbf* Wt1 = (hbf*)(ws + off); off += (size_t)G4 * KTOT * 2;
    hbf* Ring0C = (hbf*)(ws + off); off += (size_t)(NF + 1) * HSLOT * 2;
    hbf* Ring0R = (hbf*)(ws + off); off += (size_t)(NF + 1) * HSLOT * 2;

    // zeroed-every-launch region
    char* zbase = ws + off;
    hbf* Zbuf = (hbf*)(ws + off); off += (size_t)HSLOT * 2;
    hbf* H1c0 = (hbf*)(ws + off); off += (size_t)HSLOT * 2;
    hbf* H1r0 = (hbf*)(ws + off); off += (size_t)HSLOT * 2;
    hbf* H1c1 = (hbf*)(ws + off); off += (size_t)HSLOT * 2;
    hbf* H1r1 = (hbf*)(ws + off); off += (size_t)HSLOT * 2;
    unsigned* lflags = (unsigned*)(ws + off); off += (size_t)256 * 16 * 4;
    unsigned* tkt    = (unsigned*)(ws + off); off += (size_t)8 * 16 * 4;
    unsigned* bar    = (unsigned*)(ws + off); off += (size_t)BAR_WORDS * 4;
    const size_t zbytes = (size_t)((ws + off) - zbase);
    float* h1l = (float*)(ws + off); off += (size_t)HSLOT * 4;
    float* h1u = (float*)(ws + off); off += (size_t)HSLOT * 4;

    hipMemsetAsync(zbase, 0, zbytes, stream);
    // ring zero slots (slot NF) for t=0 h-reads of layer 0
    hipMemsetAsync(Ring0C + (size_t)NF * HSLOT, 0, (size_t)HSLOT * 2, stream);
    hipMemsetAsync(Ring0R + (size_t)NF * HSLOT, 0, (size_t)HSLOT * 2, stream);

    {
        const dim3 pgrid(G4 / 32, KTOT / 32);
        prep_weights_kernel<<<pgrid, 256, 0, stream>>>(w_ih0, w_hh0, Wt0);
        prep_weights_kernel<<<pgrid, 256, 0, stream>>>(w_ih1, w_hh1, Wt1);
    }

    frontend_kernel<<<(BATCH * NF) / 8, 512, 0, stream>>>(
        input_lb, input_ub, mtx1, mtx2, lin1_w, lin1_b, Xc, Xr);

    lstm_persistent<<<NBLK, 256, 0, stream>>>(
        Xc, Xr, Xc, Xr, Wt0, Wt1, b0, b1,
        Ring0C, Ring0R, Zbuf,
        H1c0, H1r0, H1c1, H1r1,
        h1l, h1u, bar, tkt, lflags);

    final_kernel<<<BATCH, 64, 0, stream>>>(h1l, h1u, lin2_w, lin2_b, out);
}